// Round 13
// baseline (388.788 us; speedup 1.0000x reference)
//
#include <hip/hip_runtime.h>
#include <hip/hip_bf16.h>

#define DD 256
#define KC 1024
#define NT 32     // 32 tiles of 32 codes

typedef __attribute__((ext_vector_type(4))) float f32x4;
typedef __attribute__((ext_vector_type(8))) short bf16x8;

#define MFMA16 __builtin_amdgcn_mfma_f32_16x16x32_bf16

// Raw barrier: LDS ordering only (T4). Global stores/prefetch stay in flight.
#define BAR() do { \
    asm volatile("s_waitcnt lgkmcnt(0)" ::: "memory"); \
    __builtin_amdgcn_s_barrier(); \
    __builtin_amdgcn_sched_barrier(0); \
} while (0)

static __device__ __forceinline__ short f2bf(float f) {
    union { float f; unsigned u; } v; v.f = f;
    unsigned u = v.u;
    unsigned r = u + 0x7fffu + ((u >> 16) & 1u);
    return (short)(r >> 16);
}
static __device__ __forceinline__ float bf2f(short s) {
    union { unsigned u; float f; } v;
    v.u = ((unsigned)(unsigned short)s) << 16;
    return v.f;
}
static __device__ __forceinline__ unsigned pk2(float a, float b) {
    return (unsigned)(unsigned short)f2bf(a) |
           ((unsigned)(unsigned short)f2bf(b) << 16);
}

// ---------------------------------------------------------------------------
// prep: W fp32 [1024][256] -> wbf bf16 [1024][256], wtbf bf16 [256][1024],
//       wsq[k] = sum_d W[k][d]^2 / 256
// ---------------------------------------------------------------------------
__global__ void prep_kernel(const float* __restrict__ w, short* __restrict__ wbf,
                            short* __restrict__ wtbf, float* __restrict__ wsq) {
    const int cod = blockIdx.x;
    const int d   = threadIdx.x;           // 256 threads
    float v = w[cod * DD + d];
    short b = f2bf(v);
    wbf[cod * DD + d] = b;
    wtbf[d * KC + cod] = b;
    float s = v * v;
    #pragma unroll
    for (int m = 32; m >= 1; m >>= 1) s += __shfl_xor(s, m, 64);
    __shared__ float ps[4];
    const int wave = threadIdx.x >> 6, lane = threadIdx.x & 63;
    if (lane == 0) ps[wave] = s;
    __syncthreads();
    if (threadIdx.x == 0) {
        wsq[cod] = (ps[0] + ps[1] + ps[2] + ps[3]) * (1.0f / (float)DD);
    }
}

// load the 8 B-fragments of score tile TILE directly global->reg (MFMA layout)
#define LOADW(W0,W1,W2,W3,W4,W5,W6,W7, TILE) do { \
    const short* _p = wbf + ((size_t)((TILE) * 32) + cg * 16 + llo) * DD + lhi * 8; \
    W0 = *(const bf16x8*)(_p      ); W1 = *(const bf16x8*)(_p +  32); \
    W2 = *(const bf16x8*)(_p +  64); W3 = *(const bf16x8*)(_p +  96); \
    W4 = *(const bf16x8*)(_p + 128); W5 = *(const bf16x8*)(_p + 160); \
    W6 = *(const bf16x8*)(_p + 192); W7 = *(const bf16x8*)(_p + 224); \
} while (0)

#define SCOREMM(W0,W1,W2,W3,W4,W5,W6,W7, SACC) do { \
    SACC = (f32x4){0.f,0.f,0.f,0.f}; \
    SACC = MFMA16(xa[0], W0, SACC, 0,0,0); \
    SACC = MFMA16(xa[1], W1, SACC, 0,0,0); \
    SACC = MFMA16(xa[2], W2, SACC, 0,0,0); \
    SACC = MFMA16(xa[3], W3, SACC, 0,0,0); \
    SACC = MFMA16(xa[4], W4, SACC, 0,0,0); \
    SACC = MFMA16(xa[5], W5, SACC, 0,0,0); \
    SACC = MFMA16(xa[6], W6, SACC, 0,0,0); \
    SACC = MFMA16(xa[7], W7, SACC, 0,0,0); \
} while (0)

#define EXPST(SACC, I) do { \
    float _e0 = __expf(SACC[0] * (1.0f/128.0f) - wscur); \
    float _e1 = __expf(SACC[1] * (1.0f/128.0f) - wscur); \
    float _e2 = __expf(SACC[2] * (1.0f/128.0f) - wscur); \
    float _e3 = __expf(SACC[3] * (1.0f/128.0f) - wscur); \
    rs[0] += _e0; rs[1] += _e1; rs[2] += _e2; rs[3] += _e3; \
    epk[I][0] = pk2(_e0, _e1); epk[I][1] = pk2(_e2, _e3); \
    wscur = wsnext; \
    if ((I) + 2 < NT) wsnext = wsq[((I) + 2) * 32 + cg * 16 + llo]; \
} while (0)

// load PV B-fragments of tile TILE directly global->reg (W^T rows d, d+16)
#define LOADPB(B0,B1, TILE) do { \
    const short* _p = wtbf + (size_t)(w * 32 + llo) * KC + (TILE) * 32 + lhi * 8; \
    B0 = *(const bf16x8*)_p; \
    B1 = *(const bf16x8*)(_p + (size_t)16 * KC); \
} while (0)

#define PVSTEP(B0,B1, I) do { \
    const int _b = (I) & 1; \
    float _q0 = bf2f((short)(epk[I][0] & 0xffff)) * inv4[0]; \
    float _q1 = bf2f((short)(epk[I][0] >> 16))    * inv4[1]; \
    float _q2 = bf2f((short)(epk[I][1] & 0xffff)) * inv4[2]; \
    float _q3 = bf2f((short)(epk[I][1] >> 16))    * inv4[3]; \
    et_[_b][(myrow0 + 0) * 36 + mycode] = f2bf(_q0); \
    et_[_b][(myrow0 + 1) * 36 + mycode] = f2bf(_q1); \
    et_[_b][(myrow0 + 2) * 36 + mycode] = f2bf(_q2); \
    et_[_b][(myrow0 + 3) * 36 + mycode] = f2bf(_q3); \
    BAR(); \
    { /* qdist full-line vectorized store */ \
      const char* _ep = (const char*)et_[_b] + qrow * 72 + c4 * 2; \
      unsigned _u0 = *(const unsigned*)_ep, _u1 = *(const unsigned*)(_ep + 4); \
      f32x4 _o; \
      _o[0] = bf2f((short)(_u0 & 0xffff)); _o[1] = bf2f((short)(_u0 >> 16)); \
      _o[2] = bf2f((short)(_u1 & 0xffff)); _o[3] = bf2f((short)(_u1 >> 16)); \
      *(f32x4*)(qbase + (size_t)qrow * KC + (size_t)(I) * 32 + c4) = _o; } \
    { bf16x8 _a0 = *(const bf16x8*)((char*)et_[_b] + (      llo) * 72 + lhi * 16); \
      bf16x8 _a1 = *(const bf16x8*)((char*)et_[_b] + (16 + llo) * 72 + lhi * 16); \
      bf16x8 _a2 = *(const bf16x8*)((char*)et_[_b] + (32 + llo) * 72 + lhi * 16); \
      bf16x8 _a3 = *(const bf16x8*)((char*)et_[_b] + (48 + llo) * 72 + lhi * 16); \
      uacc[0][0] = MFMA16(B0, _a0, uacc[0][0], 0,0,0); \
      uacc[0][1] = MFMA16(B1, _a0, uacc[0][1], 0,0,0); \
      uacc[1][0] = MFMA16(B0, _a1, uacc[1][0], 0,0,0); \
      uacc[1][1] = MFMA16(B1, _a1, uacc[1][1], 0,0,0); \
      uacc[2][0] = MFMA16(B0, _a2, uacc[2][0], 0,0,0); \
      uacc[2][1] = MFMA16(B1, _a2, uacc[2][1], 0,0,0); \
      uacc[3][0] = MFMA16(B0, _a3, uacc[3][0], 0,0,0); \
      uacc[3][1] = MFMA16(B1, _a3, uacc[3][1], 0,0,0); } \
} while (0)

// ---------------------------------------------------------------------------
// Fused kernel, 64 rows/block, 512 thr (8 waves).
// PASS 1: NO LDS, NO barriers — W score-fragments loaded global->reg in MFMA
//   layout, 2-tile ping-pong (named regs). e packed bf16 in 64 VGPRs.
// PASS 2: PV with B direct global->reg (2-deep); only et_ (q exchange, 9 KB)
//   goes through LDS; 1 raw barrier per tile.
// Removes the W global->LDS->reg round-trip that kept the LDS pipe ~80% busy
// (R12 accounting: ~96 us of LDS serialization).
// ---------------------------------------------------------------------------
__global__ __launch_bounds__(512, 2) void fused_kernel(
    const float* __restrict__ x, const short* __restrict__ wbf,
    const short* __restrict__ wtbf, const float* __restrict__ wsq,
    float* __restrict__ qdist, float* __restrict__ quant)
{
    __shared__ short et_[2][64 * 36];     // 4.6 KB each: q bf16 [row][32+4pad]
    __shared__ float red_[2][64];
    __shared__ float invs_[64];

    const int t   = threadIdx.x;
    const int w   = t >> 6, l = t & 63;
    const int lhi = l >> 4, llo = l & 15;
    const int rg  = w >> 1, cg = w & 1;
    const long rowbase = (long)blockIdx.x * 64;

    const int mycode = cg * 16 + llo;
    const int myrow0 = rg * 16 + lhi * 4;
    const int qrow = t >> 3, c4 = (t & 7) * 4;

    // ---- W tile0/1 prefetch (issued first, covered by x load) ----
    bf16x8 wA0,wA1,wA2,wA3,wA4,wA5,wA6,wA7;
    bf16x8 wB0,wB1,wB2,wB3,wB4,wB5,wB6,wB7;
    LOADW(wA0,wA1,wA2,wA3,wA4,wA5,wA6,wA7, 0);
    LOADW(wB0,wB1,wB2,wB3,wB4,wB5,wB6,wB7, 1);

    // ---- x fragments ----
    bf16x8 xa[8];
    {
        const float* xr = x + (rowbase + rg * 16 + llo) * DD + lhi * 8;
        #pragma unroll
        for (int kk = 0; kk < 8; kk++) {
            f32x4 v0 = *(const f32x4*)(xr + kk * 32);
            f32x4 v1 = *(const f32x4*)(xr + kk * 32 + 4);
            bf16x8 b;
            b[0]=f2bf(v0[0]); b[1]=f2bf(v0[1]); b[2]=f2bf(v0[2]); b[3]=f2bf(v0[3]);
            b[4]=f2bf(v1[0]); b[5]=f2bf(v1[1]); b[6]=f2bf(v1[2]); b[7]=f2bf(v1[3]);
            xa[kk] = b;
        }
    }

    float wscur  = wsq[cg * 16 + llo];
    float wsnext = wsq[32 + cg * 16 + llo];

    float rs[4] = {0.f, 0.f, 0.f, 0.f};
    unsigned epk[NT][2];                 // packed bf16 e — stays in VGPRs

    // =================== PASS 1: scores (no LDS, no barriers) ==============
    f32x4 sA, sB;
    #pragma unroll
    for (int i = 0; i < NT; i += 2) {
        SCOREMM(wA0,wA1,wA2,wA3,wA4,wA5,wA6,wA7, sA);
        if (i + 2 < NT) LOADW(wA0,wA1,wA2,wA3,wA4,wA5,wA6,wA7, i + 2);
        EXPST(sA, i);
        SCOREMM(wB0,wB1,wB2,wB3,wB4,wB5,wB6,wB7, sB);
        if (i + 3 < NT) LOADW(wB0,wB1,wB2,wB3,wB4,wB5,wB6,wB7, i + 3);
        EXPST(sB, i + 1);
    }

    // ---- PV tile0/1 B prefetch (cover under the reduction) ----
    bf16x8 bbA0, bbA1, bbB0, bbB1;
    LOADPB(bbA0, bbA1, 0);
    LOADPB(bbB0, bbB1, 1);

    // ---- rowsum reduce -> invs ----
    #pragma unroll
    for (int m = 1; m <= 8; m <<= 1)
        #pragma unroll
        for (int r = 0; r < 4; r++) rs[r] += __shfl_xor(rs[r], m, 64);
    if (llo == 0) {
        #pragma unroll
        for (int r = 0; r < 4; r++) red_[cg][rg * 16 + lhi * 4 + r] = rs[r];
    }
    __syncthreads();
    if (t < 64) invs_[t] = 1.0f / (red_[0][t] + red_[1][t]);
    __syncthreads();

    float inv4[4];
    #pragma unroll
    for (int r = 0; r < 4; r++) inv4[r] = invs_[rg * 16 + lhi * 4 + r];

    f32x4 uacc[4][2];   // transposed PV: D[d][row]
    #pragma unroll
    for (int a = 0; a < 4; a++)
        #pragma unroll
        for (int b = 0; b < 2; b++) uacc[a][b] = (f32x4){0.f, 0.f, 0.f, 0.f};

    float* qbase = qdist + rowbase * KC;

    // =================== PASS 2: PV + outputs (1 barrier/tile) =============
    #pragma unroll
    for (int i = 0; i < NT; i += 2) {
        PVSTEP(bbA0, bbA1, i);
        if (i + 2 < NT) LOADPB(bbA0, bbA1, i + 2);
        PVSTEP(bbB0, bbB1, i + 1);
        if (i + 3 < NT) LOADPB(bbB0, bbB1, i + 3);
    }

    // quant stores: uacc[rowg][dg] = D[d][row] -> f32x4 along d
    #pragma unroll
    for (int rowg = 0; rowg < 4; rowg++)
        #pragma unroll
        for (int dg = 0; dg < 2; dg++)
            *(f32x4*)(quant + (rowbase + rowg * 16 + llo) * DD + w * 32 + dg * 16 + lhi * 4)
                = uacc[rowg][dg];
}

// ---------------------------------------------------------------------------
extern "C" void kernel_launch(void* const* d_in, const int* in_sizes, int n_in,
                              void* d_out, int out_size, void* d_ws, size_t ws_size,
                              hipStream_t stream) {
    const float* x = (const float*)d_in[0];
    const float* w = (const float*)d_in[1];
    float* out = (float*)d_out;

    const int nrows = in_sizes[0] / DD;          // 65536
    float* quant = out;                          // [nrows][256]
    float* qdist = out + (size_t)nrows * DD;     // [nrows][1024]

    short* wbf  = (short*)d_ws;                  // 1024*256 bf16 = 512 KB
    short* wtbf = wbf + (size_t)KC * DD;         // 256*1024 bf16 = 512 KB
    float* wsq  = (float*)(wtbf + (size_t)DD * KC);  // 1024 fp32

    prep_kernel<<<KC, DD, 0, stream>>>(w, wbf, wtbf, wsq);
    fused_kernel<<<nrows / 64, 512, 0, stream>>>(x, wbf, wtbf, wsq, qdist, quant);
}

// Round 14
// 187.847 us; speedup vs baseline: 2.0697x; 2.0697x over previous
//
#include <hip/hip_runtime.h>
#include <hip/hip_bf16.h>

#define DD 256
#define KC 1024
#define NT1 16    // pass-1: 16 tiles of 64 codes
#define NT2 32    // pass-2: 32 tiles of 32 codes

typedef __attribute__((ext_vector_type(4))) float f32x4;
typedef __attribute__((ext_vector_type(8))) short bf16x8;

#define MFMA16 __builtin_amdgcn_mfma_f32_16x16x32_bf16

// Raw barrier: LDS ordering only (T4). Global stores/prefetch stay in flight.
#define BAR() do { \
    asm volatile("s_waitcnt lgkmcnt(0)" ::: "memory"); \
    __builtin_amdgcn_s_barrier(); \
    __builtin_amdgcn_sched_barrier(0); \
} while (0)

static __device__ __forceinline__ short f2bf(float f) {
    union { float f; unsigned u; } v; v.f = f;
    unsigned u = v.u;
    unsigned r = u + 0x7fffu + ((u >> 16) & 1u);
    return (short)(r >> 16);
}
static __device__ __forceinline__ float bf2f(short s) {
    union { unsigned u; float f; } v;
    v.u = ((unsigned)(unsigned short)s) << 16;
    return v.f;
}
static __device__ __forceinline__ unsigned pk2(float a, float b) {
    return (unsigned)(unsigned short)f2bf(a) |
           ((unsigned)(unsigned short)f2bf(b) << 16);
}

// ---------------------------------------------------------------------------
// prep: W fp32 [1024][256] -> wbf bf16 [1024][256], wtbf bf16 [256][1024],
//       wsq[k] = sum_d W[k][d]^2 / 256
// ---------------------------------------------------------------------------
__global__ void prep_kernel(const float* __restrict__ w, short* __restrict__ wbf,
                            short* __restrict__ wtbf, float* __restrict__ wsq) {
    const int cod = blockIdx.x;
    const int d   = threadIdx.x;           // 256 threads
    float v = w[cod * DD + d];
    short b = f2bf(v);
    wbf[cod * DD + d] = b;
    wtbf[d * KC + cod] = b;
    float s = v * v;
    #pragma unroll
    for (int m = 32; m >= 1; m >>= 1) s += __shfl_xor(s, m, 64);
    __shared__ float ps[4];
    const int wave = threadIdx.x >> 6, lane = threadIdx.x & 63;
    if (lane == 0) ps[wave] = s;
    __syncthreads();
    if (threadIdx.x == 0) {
        wsq[cod] = (ps[0] + ps[1] + ps[2] + ps[3]) * (1.0f / (float)DD);
    }
}

// ---------------------------------------------------------------------------
// Fused kernel, 64 rows/block, 512 thr (8 waves = rg[2 row-halves] x cg[4
// code-strips]).
// PASS 1 (16 tiles x 64 codes): W staged to LDS (dbuf, XOR-swizzled,
//   coalesced global loads); each wave holds 32 x-rows in regs (xa[2][8]) so
//   every W-fragment read feeds TWO MFMAs (reads/MFMA 1.0 -> 0.5; pass-1 LDS
//   reads halved vs R12). e packed bf16 in 64 VGPRs.
// PASS 2 (32 tiles x 32 codes): verbatim R12 PV (already 4x bb reuse); et
//   written by the 4 waves whose cg-half owns the tile's codes.
// __launch_bounds__(512,2): VGPR cap 256 — epk must NOT spill (R12 lesson).
// ---------------------------------------------------------------------------
__global__ __launch_bounds__(512, 2) void fused_kernel(
    const float* __restrict__ x, const short* __restrict__ wbf,
    const short* __restrict__ wtbf, const float* __restrict__ wsq,
    float* __restrict__ qdist, float* __restrict__ quant)
{
    __shared__ short wt_[2][64 * DD];     // 32 KB each: [code][256 d], swizzled
    __shared__ short wtT_[2][128 * 64];   // 16 KB each: superrow layout, swizzled
    __shared__ short et_[2][64 * 36];     // 4.6 KB each: q bf16 [row][32+4pad]
    __shared__ float red_[4][64];
    __shared__ float invs_[64];

    const int t   = threadIdx.x;
    const int w   = t >> 6, l = t & 63;
    const int lhi = l >> 4, llo = l & 15;
    const int rg  = w >> 2, cg = w & 3;
    const long rowbase = (long)blockIdx.x * 64;

    // pass-1 staging identity: 64-code tile = 32 KB; 64B/thread
    const int sc1 = t >> 3;              // code 0..63
    const int gq  = (t & 7) * 4;         // granule base 0,4,...,28
    // pass-2 wtT staging identity (R12)
    const int sd  = t >> 1;              // d 0..255
    const int sg2 = (t & 1) * 2;
    const int ssr = sd >> 1;
    const int shb = (sd & 1) * 4;

    bf16x8 wpf[4];

    // ---- issue W tile0 loads ----
    {
        const short* p = wbf + (size_t)sc1 * DD + gq * 8;
        #pragma unroll
        for (int j = 0; j < 4; j++) wpf[j] = *(const bf16x8*)(p + j * 8);
    }

    // ---- x fragments: 32 rows/wave (rows rg*32 + g*16 + llo) ----
    bf16x8 xa[2][8];
    #pragma unroll
    for (int g = 0; g < 2; g++) {
        const float* xr = x + (rowbase + rg * 32 + g * 16 + llo) * DD + lhi * 8;
        #pragma unroll
        for (int kk = 0; kk < 8; kk++) {
            f32x4 v0 = *(const f32x4*)(xr + kk * 32);
            f32x4 v1 = *(const f32x4*)(xr + kk * 32 + 4);
            bf16x8 b;
            b[0]=f2bf(v0[0]); b[1]=f2bf(v0[1]); b[2]=f2bf(v0[2]); b[3]=f2bf(v0[3]);
            b[4]=f2bf(v1[0]); b[5]=f2bf(v1[1]); b[6]=f2bf(v1[2]); b[7]=f2bf(v1[3]);
            xa[g][kk] = b;
        }
    }

    // ---- stage W tile0 -> wt_[0]; load tile1 ----
    #pragma unroll
    for (int j = 0; j < 4; j++)
        *(bf16x8*)((char*)wt_[0] + sc1 * 512 + (((gq + j) ^ (sc1 & 7)) << 4)) = wpf[j];
    {
        const short* p = wbf + (size_t)(64 + sc1) * DD + gq * 8;
        #pragma unroll
        for (int j = 0; j < 4; j++) wpf[j] = *(const bf16x8*)(p + j * 8);
    }

    const int mycode = cg * 16 + llo;      // code within 64-tile, 0..63
    const int cswz   = mycode & 7;
    float wscur  = wsq[mycode];
    float wsnext = wsq[64 + mycode];

    float rs[2][4] = {{0.f,0.f,0.f,0.f},{0.f,0.f,0.f,0.f}};
    unsigned epk[NT1][2][2];               // [tile][rowgrp][pair] — VGPRs only

    // =================== PASS 1: scores -> e in registers ===================
    #pragma unroll
    for (int i = 0; i < NT1; i++) {
        BAR();
        if (i < NT1 - 1) {                 // stage tile i+1 -> wt_[(i+1)&1]
            char* wb = (char*)wt_[(i + 1) & 1] + sc1 * 512;
            #pragma unroll
            for (int j = 0; j < 4; j++)
                *(bf16x8*)(wb + (((gq + j) ^ (sc1 & 7)) << 4)) = wpf[j];
        }
        if (i < NT1 - 2) {                 // load tile i+2
            const short* p = wbf + (size_t)((i + 2) * 64 + sc1) * DD + gq * 8;
            #pragma unroll
            for (int j = 0; j < 4; j++) wpf[j] = *(const bf16x8*)(p + j * 8);
        }
        char* wb2 = (char*)wt_[i & 1] + mycode * 512;
        f32x4 s0 = {0.f,0.f,0.f,0.f}, s1 = {0.f,0.f,0.f,0.f};
        #pragma unroll
        for (int kk = 0; kk < 8; kk++) {
            bf16x8 bb = *(const bf16x8*)(wb2 + (((kk * 4 + lhi) ^ cswz) << 4));
            s0 = MFMA16(xa[0][kk], bb, s0, 0, 0, 0);
            s1 = MFMA16(xa[1][kk], bb, s1, 0, 0, 0);
        }
        {
            float e0 = __expf(s0[0] * (1.0f/128.0f) - wscur);
            float e1 = __expf(s0[1] * (1.0f/128.0f) - wscur);
            float e2 = __expf(s0[2] * (1.0f/128.0f) - wscur);
            float e3 = __expf(s0[3] * (1.0f/128.0f) - wscur);
            rs[0][0] += e0; rs[0][1] += e1; rs[0][2] += e2; rs[0][3] += e3;
            epk[i][0][0] = pk2(e0, e1); epk[i][0][1] = pk2(e2, e3);
        }
        {
            float e0 = __expf(s1[0] * (1.0f/128.0f) - wscur);
            float e1 = __expf(s1[1] * (1.0f/128.0f) - wscur);
            float e2 = __expf(s1[2] * (1.0f/128.0f) - wscur);
            float e3 = __expf(s1[3] * (1.0f/128.0f) - wscur);
            rs[1][0] += e0; rs[1][1] += e1; rs[1][2] += e2; rs[1][3] += e3;
            epk[i][1][0] = pk2(e0, e1); epk[i][1][1] = pk2(e2, e3);
        }
        wscur = wsnext;
        if (i < NT1 - 2) wsnext = wsq[(i + 2) * 64 + mycode];
    }

    // ---- issue wtT tile0 loads early (cover under reduction) ----
    bf16x8 tpf0, tpf1;
    { const short* p = wtbf + (size_t)sd * KC + sg2 * 8;
      tpf0 = *(const bf16x8*)p; tpf1 = *(const bf16x8*)(p + 8); }

    // ---- rowsum reduce -> invs ----
    #pragma unroll
    for (int m = 1; m <= 8; m <<= 1)
        #pragma unroll
        for (int g = 0; g < 2; g++)
            #pragma unroll
            for (int r = 0; r < 4; r++)
                rs[g][r] += __shfl_xor(rs[g][r], m, 64);
    if (llo == 0) {
        #pragma unroll
        for (int g = 0; g < 2; g++)
            #pragma unroll
            for (int r = 0; r < 4; r++)
                red_[cg][rg * 32 + g * 16 + lhi * 4 + r] = rs[g][r];
    }
    __syncthreads();
    if (t < 64) invs_[t] = 1.0f / (red_[0][t] + red_[1][t] + red_[2][t] + red_[3][t]);
    __syncthreads();

    float inv8[2][4];
    #pragma unroll
    for (int g = 0; g < 2; g++)
        #pragma unroll
        for (int r = 0; r < 4; r++)
            inv8[g][r] = invs_[rg * 32 + g * 16 + lhi * 4 + r];

    f32x4 uacc[4][2];   // transposed PV: D[d][row] (R9/R12-verified map)
    #pragma unroll
    for (int a = 0; a < 4; a++)
        #pragma unroll
        for (int b = 0; b < 2; b++) uacc[a][b] = (f32x4){0.f, 0.f, 0.f, 0.f};

    float* qbase = qdist + rowbase * KC;
    const int qrow = t >> 3, c4 = (t & 7) * 4;   // qdist store identity
    const int ci   = (cg & 1) * 16 + llo;        // code-in-32-tile for et writes
    const int chalf = cg >> 1;                   // which 32-half this wave holds

    // =================== PASS 2: PV + outputs (verbatim R12 core) ==========
    #pragma unroll
    for (int k = 0; k < NT2; k++) {
        const int b = k & 1;
        // et write: only waves whose cg-half owns codes [k*32, k*32+32)
        if (chalf == (k & 1)) {
            const int t16 = k >> 1;
            #pragma unroll
            for (int g = 0; g < 2; g++) {
                const unsigned p0 = epk[t16][g][0], p1 = epk[t16][g][1];
                const int row0 = rg * 32 + g * 16 + lhi * 4;
                et_[b][(row0 + 0) * 36 + ci] = f2bf(bf2f((short)(p0 & 0xffff)) * inv8[g][0]);
                et_[b][(row0 + 1) * 36 + ci] = f2bf(bf2f((short)(p0 >> 16))    * inv8[g][1]);
                et_[b][(row0 + 2) * 36 + ci] = f2bf(bf2f((short)(p1 & 0xffff)) * inv8[g][2]);
                et_[b][(row0 + 3) * 36 + ci] = f2bf(bf2f((short)(p1 >> 16))    * inv8[g][3]);
            }
        }
        // stage wtT tile k -> wtT_[b]
        {
            char* tb = (char*)wtT_[b] + ssr * 128;
            *(bf16x8*)(tb + (((shb + sg2    ) ^ (ssr & 7)) << 4)) = tpf0;
            *(bf16x8*)(tb + (((shb + sg2 + 1) ^ (ssr & 7)) << 4)) = tpf1;
        }
        if (k < NT2 - 1) {                 // load wtT tile k+1
            const short* p = wtbf + (size_t)sd * KC + (k + 1) * 32 + sg2 * 8;
            tpf0 = *(const bf16x8*)p; tpf1 = *(const bf16x8*)(p + 8);
        }
        BAR();
        // qdist store, full-line vectorized: 4 bf16 from et_ -> one f32x4
        {
            const char* ep = (const char*)et_[b] + qrow * 72 + c4 * 2;
            unsigned u0 = *(const unsigned*)ep;
            unsigned u1 = *(const unsigned*)(ep + 4);
            f32x4 o;
            o[0] = bf2f((short)(u0 & 0xffff)); o[1] = bf2f((short)(u0 >> 16));
            o[2] = bf2f((short)(u1 & 0xffff)); o[3] = bf2f((short)(u1 >> 16));
            *(f32x4*)(qbase + (size_t)qrow * KC + (size_t)k * 32 + c4) = o;
        }
        // PV from et_[b] + wtT_[b]
        bf16x8 bb0, bb1;
        {
            const int d0 = w * 32 + llo;
            bb0 = *(const bf16x8*)((char*)wtT_[b] + (d0 >> 1) * 128 +
                    (((((d0 & 1) << 2) + lhi) ^ ((d0 >> 1) & 7)) << 4));
            const int d1 = w * 32 + 16 + llo;
            bb1 = *(const bf16x8*)((char*)wtT_[b] + (d1 >> 1) * 128 +
                    (((((d1 & 1) << 2) + lhi) ^ ((d1 >> 1) & 7)) << 4));
        }
        #pragma unroll
        for (int rowg = 0; rowg < 4; rowg++) {
            bf16x8 aa = *(const bf16x8*)((char*)et_[b] + (rowg * 16 + llo) * 72 + lhi * 16);
            uacc[rowg][0] = MFMA16(bb0, aa, uacc[rowg][0], 0, 0, 0);
            uacc[rowg][1] = MFMA16(bb1, aa, uacc[rowg][1], 0, 0, 0);
        }
    }

    // quant stores: uacc[rowg][dg] = D[d][row] -> f32x4 along d
    #pragma unroll
    for (int rowg = 0; rowg < 4; rowg++)
        #pragma unroll
        for (int dg = 0; dg < 2; dg++)
            *(f32x4*)(quant + (rowbase + rowg * 16 + llo) * DD + w * 32 + dg * 16 + lhi * 4)
                = uacc[rowg][dg];
}

// ---------------------------------------------------------------------------
extern "C" void kernel_launch(void* const* d_in, const int* in_sizes, int n_in,
                              void* d_out, int out_size, void* d_ws, size_t ws_size,
                              hipStream_t stream) {
    const float* x = (const float*)d_in[0];
    const float* w = (const float*)d_in[1];
    float* out = (float*)d_out;

    const int nrows = in_sizes[0] / DD;          // 65536
    float* quant = out;                          // [nrows][256]
    float* qdist = out + (size_t)nrows * DD;     // [nrows][1024]

    short* wbf  = (short*)d_ws;                  // 1024*256 bf16 = 512 KB
    short* wtbf = wbf + (size_t)KC * DD;         // 256*1024 bf16 = 512 KB
    float* wsq  = (float*)(wtbf + (size_t)DD * KC);  // 1024 fp32

    prep_kernel<<<KC, DD, 0, stream>>>(w, wbf, wtbf, wsq);
    fused_kernel<<<nrows / 64, 512, 0, stream>>>(x, wbf, wtbf, wsq, qdist, quant);
}